// Round 1
// 327.724 us; speedup vs baseline: 1.0922x; 1.0922x over previous
//
#include <hip/hip_runtime.h>
#include <hip/hip_fp16.h>

#define N_NODES   100000
#define N_EDGES   3200000
#define F_IN      256
#define HID       16
#define NCLS      40

#define CHUNK     16384
#define NBLK      ((N_EDGES + CHUNK - 1) / CHUNK)    // 196 edge chunks
#define B2SHIFT   9                                  // 512 nodes per coarse bucket
#define NB2       ((N_NODES + 511) >> B2SHIFT)       // 196 buckets
#define BCAP      17408                              // LDS edge cache in build (mean 16384, +8 sigma)

// ---- phase A: per-chunk histogram over coarse dst buckets (LDS atomics only) ----
__global__ __launch_bounds__(256) void hist_kernel(const int* __restrict__ ei,
                                                   int* __restrict__ hist_blk) {
    __shared__ int h[NB2];
    int blk = blockIdx.x, t = threadIdx.x;
    for (int i = t; i < NB2; i += 256) h[i] = 0;
    __syncthreads();
    int e0 = blk * CHUNK;
    int eN = min(CHUNK, N_EDGES - e0);               // always %4 == 0
    const int4* d4 = (const int4*)(ei + N_EDGES + e0);
    for (int i = t; i < (eN >> 2); i += 256) {
        int4 d = d4[i];
        atomicAdd(&h[d.x >> B2SHIFT], 1);
        atomicAdd(&h[d.y >> B2SHIFT], 1);
        atomicAdd(&h[d.z >> B2SHIFT], 1);
        atomicAdd(&h[d.w >> B2SHIFT], 1);
    }
    __syncthreads();
    for (int i = t; i < NB2; i += 256) hist_blk[i * NBLK + blk] = h[i];  // bucket-major
}

// ---- phase B: exclusive scan within each bucket row (over blocks) + row totals ----
__global__ __launch_bounds__(256) void rowscan_kernel(int* __restrict__ hist_blk,
                                                      int* __restrict__ rowsum) {
    __shared__ int part[256];
    int b = blockIdx.x, t = threadIdx.x;
    int v = (t < NBLK) ? hist_blk[b * NBLK + t] : 0;
    part[t] = v;
    __syncthreads();
    for (int off = 1; off < 256; off <<= 1) {
        int u = (t >= off) ? part[t - off] : 0;
        __syncthreads();
        part[t] += u;
        __syncthreads();
    }
    if (t < NBLK) hist_blk[b * NBLK + t] = part[t] - v;  // exclusive within row
    if (t == 255) rowsum[b] = part[255];
}

// ---- phase C: scatter edges into deterministic disjoint sub-ranges ----
// bucket_base recomputed in-block (196-int scan ~ 200 cycles) -> basescan kernel deleted
// pack: (dst & 511) << 17 | src   (src < 2^17)
__global__ __launch_bounds__(256) void bin2_kernel(const int* __restrict__ ei,
                                                   const int* __restrict__ hist_blk,
                                                   const int* __restrict__ rowsum,
                                                   int* __restrict__ buf) {
    __shared__ int cur[NB2];
    __shared__ int sc[256];
    int blk = blockIdx.x, t = threadIdx.x;
    int rv = (t < NB2) ? rowsum[t] : 0;
    sc[t] = rv;
    __syncthreads();
    for (int off = 1; off < 256; off <<= 1) {
        int u = (t >= off) ? sc[t - off] : 0;
        __syncthreads();
        sc[t] += u;
        __syncthreads();
    }
    if (t < NB2) cur[t] = (sc[t] - rv) + hist_blk[t * NBLK + blk];
    __syncthreads();
    int e0 = blk * CHUNK;
    int eN = min(CHUNK, N_EDGES - e0);               // always %4 == 0
    const int4* s4 = (const int4*)(ei + e0);
    const int4* d4 = (const int4*)(ei + N_EDGES + e0);
    for (int i = t; i < (eN >> 2); i += 256) {
        int4 d = d4[i], s = s4[i];
        int p0 = atomicAdd(&cur[d.x >> B2SHIFT], 1); buf[p0] = ((d.x & 511) << 17) | s.x;
        int p1 = atomicAdd(&cur[d.y >> B2SHIFT], 1); buf[p1] = ((d.y & 511) << 17) | s.y;
        int p2 = atomicAdd(&cur[d.z >> B2SHIFT], 1); buf[p2] = ((d.z & 511) << 17) | s.z;
        int p3 = atomicAdd(&cur[d.w >> B2SHIFT], 1); buf[p3] = ((d.w & 511) << 17) | s.w;
    }
}

// ---- phase D: per-bucket fine build -> rowptr, dinv, csr_src (bucket cached in LDS) ----
__global__ __launch_bounds__(512) void build_kernel(const int* __restrict__ buf,
                                                    const int* __restrict__ rowsum,
                                                    int* __restrict__ rowptr,
                                                    float* __restrict__ dinv,
                                                    int* __restrict__ csr_src) {
    __shared__ int lbuf[BCAP];
    __shared__ int hist[512], offs[512], cur[512];
    __shared__ int sc[256];
    int b = blockIdx.x, t = threadIdx.x;
    int rv = 0;
    if (t < 256) { rv = (t < NB2) ? rowsum[t] : 0; sc[t] = rv; }
    hist[t] = 0;
    __syncthreads();
    for (int off = 1; off < 256; off <<= 1) {
        int u = (t < 256 && t >= off) ? sc[t - off] : 0;
        __syncthreads();
        if (t < 256) sc[t] += u;
        __syncthreads();
    }
    int cnt  = rowsum[b];
    int base = sc[b] - cnt;                          // exclusive scan of rowsum at b
    for (int i = t; i < cnt; i += 512) {
        int v = buf[base + i];
        if (i < BCAP) lbuf[i] = v;
        atomicAdd(&hist[v >> 17], 1);
    }
    __syncthreads();
    int v = hist[t];
    offs[t] = v;
    __syncthreads();
    for (int off = 1; off < 512; off <<= 1) {
        int u = (t >= off) ? offs[t - off] : 0;
        __syncthreads();
        offs[t] += u;
        __syncthreads();
    }
    int ex = offs[t] - v;   // exclusive scan
    int n = (b << B2SHIFT) + t;
    if (n < N_NODES) {
        rowptr[n] = base + ex;
        dinv[n]   = rsqrtf((float)(v + 1));  // +1 self-loop
    }
    if (b == 0 && t == 0) rowptr[N_NODES] = N_EDGES;
    cur[t] = ex;
    __syncthreads();
    for (int i = t; i < cnt; i += 512) {
        int p = (i < BCAP) ? lbuf[i] : buf[base + i];
        int pos = atomicAdd(&cur[p >> 17], 1);        // LDS atomic
        csr_src[base + pos] = p & 0x1FFFF;
    }
}

// ---------------- layer-1 GEMM: y1h[n,h] = fp16( dinv[n] * sum_k x[n,k]*W1[k,h] ) ----------------
// 2 nodes/thread: halves the uniform ds_read stream per node (was 1:4 LDS:FMA, now 1:8)
__global__ __launch_bounds__(256) void gemm1_kernel(const float* __restrict__ x,
                                                    const float* __restrict__ W1,
                                                    const float* __restrict__ dinv,
                                                    __half* __restrict__ y1h) {
    __shared__ float W1s[F_IN * HID];
    int t = threadIdx.x;
    #pragma unroll
    for (int i = 0; i < (F_IN * HID) / 256; i++) W1s[t + i * 256] = W1[t + i * 256];
    __syncthreads();

    int n0 = blockIdx.x * 512 + t;
    int n1 = n0 + 256;
    if (n0 >= N_NODES) return;
    bool v1 = (n1 < N_NODES);

    const float4* xr0 = (const float4*)(x + (size_t)n0 * F_IN);
    const float4* xr1 = (const float4*)(x + (size_t)(v1 ? n1 : n0) * F_IN);  // safe dummy
    float acc0[HID], acc1[HID];
    #pragma unroll
    for (int h = 0; h < HID; h++) { acc0[h] = 0.f; acc1[h] = 0.f; }

    #pragma unroll 2
    for (int k4 = 0; k4 < F_IN / 4; k4++) {
        float4 xa = xr0[k4];
        float4 xb = xr1[k4];
        int k = k4 * 4;
        #pragma unroll
        for (int h = 0; h < HID; h++) {
            float w0 = W1s[(k + 0) * HID + h];
            float w1 = W1s[(k + 1) * HID + h];
            float w2 = W1s[(k + 2) * HID + h];
            float w3 = W1s[(k + 3) * HID + h];
            acc0[h] += xa.x * w0 + xa.y * w1 + xa.z * w2 + xa.w * w3;
            acc1[h] += xb.x * w0 + xb.y * w1 + xb.z * w2 + xb.w * w3;
        }
    }
    {
        float dv = dinv[n0];
        __half2 hp[8];
        #pragma unroll
        for (int j = 0; j < 8; j++)
            hp[j] = __float22half2_rn(make_float2(acc0[2 * j] * dv, acc0[2 * j + 1] * dv));
        float4* o = (float4*)(y1h + (size_t)n0 * HID);
        o[0] = ((float4*)hp)[0];
        o[1] = ((float4*)hp)[1];
    }
    if (v1) {
        float dv = dinv[n1];
        __half2 hp[8];
        #pragma unroll
        for (int j = 0; j < 8; j++)
            hp[j] = __float22half2_rn(make_float2(acc1[2 * j] * dv, acc1[2 * j + 1] * dv));
        float4* o = (float4*)(y1h + (size_t)n1 * HID);
        o[0] = ((float4*)hp)[0];
        o[1] = ((float4*)hp)[1];
    }
}

// ---- helper: accumulate one fp16 row (16 halfs as 2 float4) into acc[16] ----
__device__ __forceinline__ void acc_row(const float4* __restrict__ tab, int s, float* acc) {
    float4 v0 = tab[(size_t)s * 2 + 0];
    float4 v1 = tab[(size_t)s * 2 + 1];
    const __half2* a0 = (const __half2*)&v0;
    const __half2* a1 = (const __half2*)&v1;
    #pragma unroll
    for (int j = 0; j < 4; j++) {
        float2 f0 = __half22float2(a0[j]);
        float2 f1 = __half22float2(a1[j]);
        acc[2 * j]         += f0.x;
        acc[2 * j + 1]     += f0.y;
        acc[8 + 2 * j]     += f1.x;
        acc[8 + 2 * j + 1] += f1.y;
    }
}

// ---- helper: accumulate two fp16 rows with all 4 loads in flight (latency hiding) ----
__device__ __forceinline__ void acc_row2(const float4* __restrict__ tab, int s0, int s1, float* acc) {
    float4 v0 = tab[(size_t)s0 * 2 + 0];
    float4 v1 = tab[(size_t)s0 * 2 + 1];
    float4 v2 = tab[(size_t)s1 * 2 + 0];
    float4 v3 = tab[(size_t)s1 * 2 + 1];
    const __half2* a0 = (const __half2*)&v0;
    const __half2* a1 = (const __half2*)&v1;
    const __half2* b0 = (const __half2*)&v2;
    const __half2* b1 = (const __half2*)&v3;
    #pragma unroll
    for (int j = 0; j < 4; j++) {
        float2 f0 = __half22float2(a0[j]);
        float2 f1 = __half22float2(a1[j]);
        float2 g0 = __half22float2(b0[j]);
        float2 g1 = __half22float2(b1[j]);
        acc[2 * j]         += f0.x + g0.x;
        acc[2 * j + 1]     += f0.y + g0.y;
        acc[8 + 2 * j]     += f1.x + g1.x;
        acc[8 + 2 * j + 1] += f1.y + g1.y;
    }
}

// ---------------- gather 1 (wave-coop, 16 lanes/node): zh = fp16(dinv*relu(dinv*agg + b1)) ----------------
__global__ __launch_bounds__(256) void gather1_kernel(const int* __restrict__ rowptr,
                                                      const int* __restrict__ csr_src,
                                                      const __half* __restrict__ y1h,
                                                      const float* __restrict__ b1,
                                                      const float* __restrict__ dinv,
                                                      __half* __restrict__ zh) {
    int n   = blockIdx.x * 16 + (threadIdx.x >> 4);
    int sub = threadIdx.x & 15;
    const float4* tab = (const float4*)y1h;
    int beg = rowptr[n], end = rowptr[n + 1];
    float acc[16];
    #pragma unroll
    for (int i = 0; i < 16; i++) acc[i] = 0.f;
    if (sub == 0) acc_row(tab, n, acc);               // self-loop
    int e = beg + sub;
    for (; e + 16 < end; e += 32)
        acc_row2(tab, csr_src[e], csr_src[e + 16], acc);
    if (e < end) acc_row(tab, csr_src[e], acc);
    // butterfly reduce across the 16-lane group
    #pragma unroll
    for (int m = 1; m < 16; m <<= 1) {
        #pragma unroll
        for (int i = 0; i < 16; i++) acc[i] += __shfl_xor(acc[i], m, 16);
    }
    if (sub < 2) {
        float dv = dinv[n];
        const float4* b1q = (const float4*)b1;
        float4 ba = b1q[sub * 2], bb = b1q[sub * 2 + 1];
        float bv[8] = {ba.x, ba.y, ba.z, ba.w, bb.x, bb.y, bb.z, bb.w};
        __half2 outp[4];
        #pragma unroll
        for (int j = 0; j < 4; j++) {
            float2 r;
            r.x = fmaxf(dv * acc[sub * 8 + 2 * j]     + bv[2 * j],     0.f) * dv;
            r.y = fmaxf(dv * acc[sub * 8 + 2 * j + 1] + bv[2 * j + 1], 0.f) * dv;
            outp[j] = __float22half2_rn(r);
        }
        *(float4*)(zh + (size_t)n * HID + sub * 8) = *(float4*)outp;
    }
}

// ---------------- gather 2 + output GEMM fused: out[n,c] = dinv*(agg@W2)[c] + b2[c] ----------------
__global__ __launch_bounds__(256) void gather2_kernel(const int* __restrict__ rowptr,
                                                      const int* __restrict__ csr_src,
                                                      const __half* __restrict__ zh,
                                                      const float* __restrict__ W2,
                                                      const float* __restrict__ b2,
                                                      const float* __restrict__ dinv,
                                                      float* __restrict__ out) {
    __shared__ float W2s[HID * NCLS];   // 640 floats
    __shared__ float b2s[NCLS];
    int t = threadIdx.x;
    for (int i = t; i < HID * NCLS; i += 256) W2s[i] = W2[i];
    if (t < NCLS) b2s[t] = b2[t];
    __syncthreads();

    int n   = blockIdx.x * 16 + (t >> 4);
    int sub = t & 15;
    const float4* tab = (const float4*)zh;
    int beg = rowptr[n], end = rowptr[n + 1];
    float acc[16];
    #pragma unroll
    for (int i = 0; i < 16; i++) acc[i] = 0.f;
    if (sub == 0) acc_row(tab, n, acc);               // self-loop
    int e = beg + sub;
    for (; e + 16 < end; e += 32)
        acc_row2(tab, csr_src[e], csr_src[e + 16], acc);
    if (e < end) acc_row(tab, csr_src[e], acc);
    #pragma unroll
    for (int m = 1; m < 16; m <<= 1) {
        #pragma unroll
        for (int i = 0; i < 16; i++) acc[i] += __shfl_xor(acc[i], m, 16);
    }
    if (sub < 10) {
        float dv = dinv[n];
        int c0 = sub * 4;
        float o0 = 0.f, o1 = 0.f, o2 = 0.f, o3 = 0.f;
        #pragma unroll
        for (int h = 0; h < HID; h++) {
            float a = acc[h];
            const float* w = &W2s[h * NCLS + c0];
            o0 += a * w[0]; o1 += a * w[1]; o2 += a * w[2]; o3 += a * w[3];
        }
        float4 r = make_float4(dv * o0 + b2s[c0],     dv * o1 + b2s[c0 + 1],
                               dv * o2 + b2s[c0 + 2], dv * o3 + b2s[c0 + 3]);
        *(float4*)(out + (size_t)n * NCLS + c0) = r;
    }
}

extern "C" void kernel_launch(void* const* d_in, const int* in_sizes, int n_in,
                              void* d_out, int out_size, void* d_ws, size_t ws_size,
                              hipStream_t stream) {
    const float* x   = (const float*)d_in[0];
    const int*   ei  = (const int*)  d_in[1];   // [2, E] int32
    const float* W1  = (const float*)d_in[2];
    const float* b1  = (const float*)d_in[3];
    const float* W2  = (const float*)d_in[4];
    const float* b2  = (const float*)d_in[5];
    float* out = (float*)d_out;

    char* ws = (char*)d_ws;
    size_t off = 0;
    int*   hist_blk = (int*)(ws + off); off += (size_t)NB2 * NBLK * 4;       // 154 KB
    int*   rowsum   = (int*)(ws + off); off += (size_t)NB2 * 4;
    off = (off + 15) & ~(size_t)15;
    int*    rowptr  = (int*)   (ws + off); off += (size_t)(N_NODES + 1) * 4;
    off = (off + 15) & ~(size_t)15;
    float*  dinv    = (float*) (ws + off); off += (size_t)N_NODES * 4;
    int*    csr_src = (int*)   (ws + off); off += (size_t)N_EDGES * 4;          // 12.8 MB
    int*    buf     = (int*)   (ws + off); off += (size_t)N_EDGES * 4;          // 12.8 MB
    __half* y1h     = (__half*)(ws + off); off += (size_t)N_NODES * HID * 2;    //  3.2 MB
    __half* zh      = (__half*)(ws + off); off += (size_t)N_NODES * HID * 2;    //  3.2 MB

    hist_kernel    <<<NBLK, 256, 0, stream>>>(ei, hist_blk);
    rowscan_kernel <<<NB2, 256, 0, stream>>>(hist_blk, rowsum);
    bin2_kernel    <<<NBLK, 256, 0, stream>>>(ei, hist_blk, rowsum, buf);
    build_kernel   <<<NB2, 512, 0, stream>>>(buf, rowsum, rowptr, dinv, csr_src);

    gemm1_kernel  <<<(N_NODES + 511) / 512, 256, 0, stream>>>(x, W1, dinv, y1h);
    gather1_kernel<<<N_NODES / 16, 256, 0, stream>>>(rowptr, csr_src, y1h, b1, dinv, zh);
    gather2_kernel<<<N_NODES / 16, 256, 0, stream>>>(rowptr, csr_src, zh, W2, b2, dinv, out);
}